// Round 7
// baseline (2138.098 us; speedup 1.0000x reference)
//
#include <hip/hip_runtime.h>
#include <cmath>

// Match XLA/numpy non-fused mul+add rounding everywhere (IoU / decode bit-faithfulness).
#pragma clang fp contract(off)

namespace {
constexpr int NIMG = 8;
constexpr int NLVL = 5;
constexpr int LH[5]   = {208,104,52,26,13};
constexpr int LW[5]   = {336,168,84,42,21};
constexpr int LSTR[5] = {4,8,16,32,64};
constexpr int HWA[5]  = {209664,52416,13104,3276,819};
constexpr int KSEL[5] = {2000,2000,2000,2000,819};
constexpr int SOFF[5] = {0,2000,4000,6000,8000};
constexpr int MTOT    = 8819;
constexpr int CAP     = 6144;          // per-(img,lvl) candidate cap (expect <= ~2600)
constexpr int NPAIR   = NIMG*NLVL;     // 40
constexpr int CCUM[5] = {52,65,69,70,71};  // cumulative ceil(HWA/4096) per level
constexpr int HBLK[5] = {52,13,4,1,1};     // hist blocks per (img,lvl)
constexpr int BLK_PER_IMG = 71;
constexpr int MASK_W  = 32;            // u64 words per NMS mask row (covers 2048 cols)
constexpr int OUTK    = 1000;
// 128-col mask tiles: rb in [0,nw), jw2 in [rb>>1, ceil(nw/2)); counts:
constexpr int NT2[5]  = {272,272,272,272,55};

// workspace byte offsets (all 16B-aligned where needed)
constexpr size_t OFF_HIST   = 0;              // 40*4096*4      = 655360
constexpr size_t OFF_PKC    = 0;              // 40*2048*4 = 327680, aliases hist (dead after hist+scan)
constexpr size_t OFF_CNT    = 655360;         // 40*4           = 160
constexpr size_t OFF_THR    = 655520;         // 40*4           = 160
constexpr size_t OFF_ARRH   = 655680;         // 40*4 arrival counters (hist->scan fusion)
constexpr size_t OFF_ARRR   = 655840;         // 40*4 arrival counters (racc->rsel fusion)
constexpr size_t OFF_ARRM   = 656000;         // 40*4 arrival counters (masks->nms fusion)
constexpr size_t OFF_RNK    = 656160;         // 40*6144*4      = 983040  -> 1639200 (zeroed)
constexpr size_t ZERO_BYTES = 1639200;        // zeroed range (hist+cnt+thr+arr*+rnk), /16 ok
constexpr size_t OFF_SELKEY = 1921120;        // 8*8819*8       = 564416  -> 2485536
constexpr size_t OFF_SELBOX = 2767744;        // 8*8819*16      = 1128832 -> 3896576
constexpr size_t OFF_MASK   = 3896576;        // 40*2000*32*8   = 20480000-> 24376576
constexpr size_t OFF_CKEY   = OFF_MASK;       // 40*6144*8 = 1.97MB aliases maskbuf (dead by k_masks)
constexpr size_t OFF_CBOX   = OFF_MASK + 2097152; // 40*6144*16 = 3.93MB, aliases maskbuf (dead by k_masks)
constexpr size_t OFF_KEEP   = 24376576;       // 40*32*8        = 10240   -> 24386816
}

struct Ins {
  const float* cls[5];
  const float* reg[5];
  const int* ih;
  const int* iw;
};

__device__ __forceinline__ void decode_block(int b, int& img, int& lvl, int& chunk) {
  img = b / BLK_PER_IMG;
  int rb = b - img*BLK_PER_IMG;
  if      (rb < CCUM[0]) { lvl=0; chunk=rb; }
  else if (rb < CCUM[1]) { lvl=1; chunk=rb-CCUM[0]; }
  else if (rb < CCUM[2]) { lvl=2; chunk=rb-CCUM[1]; }
  else if (rb < CCUM[3]) { lvl=3; chunk=rb-CCUM[2]; }
  else                   { lvl=4; chunk=0; }
}

// order-preserving float->u32 map (total order over floats)
__device__ __forceinline__ unsigned mapbits(float x) {
  unsigned u = __float_as_uint(x);
  return u ^ (unsigned)(((int)u >> 31) | (int)0x80000000);
}

// fp32 sigmoid with correctly-rounded exp step: matches 1/(1+exp_f32(-x)) pipeline
__device__ __forceinline__ float sigmoid_ref(float x) {
  float e = (float)exp(-(double)x);   // correctly-rounded f32 exp(-x)
  return 1.0f / (1.0f + e);           // exact-IEEE add + div
}

// ---- K0: fused zeroing (replaces two hipMemsetAsync launches) ----
__global__ void __launch_bounds__(256) k_zero(float* ws, float* out) {
  const int NWS  = (int)(ZERO_BYTES / 16);
  const int NOUT = NIMG*OUTK*5*4/16;
  float4* w4 = (float4*)ws;
  float4* o4 = (float4*)out;
  float4 z = make_float4(0.f,0.f,0.f,0.f);
  int i = blockIdx.x*256 + threadIdx.x, stride = gridDim.x*256;
  for (int j = i; j < NWS;  j += stride) w4[j] = z;
  for (int j = i; j < NOUT; j += stride) o4[j] = z;
}

// ---- K1: per-(img,lvl) 12-bit histogram + FUSED threshold scan (last-block).
// Last-arriving block of each pair (threadfence + device atomic arrival counter:
// launch-order independent, XCD-safe) computes the bin-edge with suffix >= k. ----
__global__ void __launch_bounds__(256) k_hist(Ins in, unsigned* __restrict__ hist,
                       unsigned* __restrict__ arrh, unsigned* __restrict__ thr) {
  int img, lvl, chunk; decode_block(blockIdx.x, img, lvl, chunk);
  int pair = img*NLVL + lvl;
  __shared__ unsigned lh[4096];
  for (int i = threadIdx.x; i < 4096; i += 256) lh[i] = 0;
  __syncthreads();
  const float* src = in.cls[lvl] + (size_t)img * HWA[lvl];
  if (lvl != 4) {                        // HWA divisible by 4, 16B-aligned per image
    const float4* src4 = (const float4*)src;
    int nf4 = HWA[lvl] >> 2;
    int base4 = chunk * 1024;
    #pragma unroll
    for (int j = 0; j < 4; j++) {
      int f = base4 + j*256 + threadIdx.x;
      if (f < nf4) {
        float4 v = src4[f];
        atomicAdd(&lh[mapbits(v.x) >> 20], 1u);
        atomicAdd(&lh[mapbits(v.y) >> 20], 1u);
        atomicAdd(&lh[mapbits(v.z) >> 20], 1u);
        atomicAdd(&lh[mapbits(v.w) >> 20], 1u);
      }
    }
  } else {                               // lvl 4: 819 elements, misaligned — scalar
    int base = chunk * 4096;
    #pragma unroll
    for (int j = 0; j < 16; j++) {
      int e = base + j*256 + threadIdx.x;
      if (e < HWA[4]) atomicAdd(&lh[mapbits(src[e]) >> 20], 1u);
    }
  }
  __syncthreads();
  unsigned* gh = hist + (size_t)pair * 4096;
  for (int i = threadIdx.x; i < 4096; i += 256)
    if (lh[i]) atomicAdd(&gh[i], lh[i]);

  // ---- fused scan: last block of this pair finds the threshold ----
  __threadfence();                       // release: lh->gh atomics ordered before arrive
  __shared__ unsigned soldh;
  if (threadIdx.x == 0) soldh = atomicAdd(&arrh[pair], 1u);
  __syncthreads();
  if (soldh != (unsigned)(HBLK[lvl] - 1)) return;
  __threadfence();                       // acquire: invalidate stale cached gh lines
  __shared__ unsigned part[256];
  unsigned s = 0;
  #pragma unroll
  for (int i = 0; i < 16; i++) s += gh[threadIdx.x*16 + i];
  part[threadIdx.x] = s;
  __syncthreads();
  if (threadIdx.x == 0) {
    unsigned k = (unsigned)KSEL[lvl];
    unsigned cum = 0;
    for (int t = 255; t >= 0; t--) {
      if (cum + part[t] >= k) {
        unsigned edge = 0;
        for (int b = t*16 + 15; b >= t*16; b--) {
          cum += gh[b];
          if (cum >= k) { edge = (unsigned)b; break; }
        }
        thr[pair] = edge << 20;
        return;
      }
      cum += part[t];
    }
    thr[pair] = 0u;
  }
}

// ---- K3: compact candidates + sort keys + FUSED box decode (scattered reg_out
// reads issue from 568 blocks of resident waves — TLP-hidden) ----
__global__ void __launch_bounds__(256) k_compact(Ins in, const unsigned* __restrict__ thr,
                          unsigned* __restrict__ cnt,
                          unsigned long long* __restrict__ ckey,
                          float4* __restrict__ cbox) {
  int img, lvl, chunk; decode_block(blockIdx.x, img, lvl, chunk);
  int pair = img*NLVL + lvl;
  unsigned T = thr[pair];
  const float* src = in.cls[lvl] + (size_t)img * HWA[lvl];
  int hw = LH[lvl] * LW[lvl];
  int lid = threadIdx.x & 63;
  __shared__ unsigned lbuf[4096];            // block covers <=4096 elements
  __shared__ unsigned long long lkey[4096];  // 32KB key staging
  __shared__ unsigned lc, gbase;
  if (threadIdx.x == 0) lc = 0;
  __syncthreads();

  auto emit = [&](int e, float v, bool sel) {
    unsigned long long mask = __ballot(sel);
    if (mask != 0ull) {
      int leader = __ffsll((long long)mask) - 1;
      unsigned wb = 0;
      if (lid == leader) wb = atomicAdd(&lc, (unsigned)__popcll(mask));  // LDS atomic
      wb = (unsigned)__shfl((int)wb, leader, 64);
      if (sel) {
        unsigned p = wb + (unsigned)__popcll(mask & ((1ull << lid) - 1ull));
        int a = e / hw;            // NCHW: e = a*hw + r
        int r = e - a*hw;
        unsigned idx = (unsigned)(r*3 + a);  // score-space idx
        lbuf[p] = idx;
        float s = sigmoid_ref(v);            // dp-exp on selected lanes only
        unsigned pack = ((unsigned)lvl << 18) | idx;   // < 2^21
        lkey[p] = ((unsigned long long)__float_as_uint(s) << 21)
                | (unsigned long long)(0x1FFFFFu - pack);  // desc score, asc (lvl,idx)
      }
    }
  };

  if (lvl != 4) {
    const float4* src4 = (const float4*)src;
    int nf4 = HWA[lvl] >> 2;
    int base4 = chunk * 1024;
    #pragma unroll
    for (int j = 0; j < 4; j++) {
      int f = base4 + j*256 + threadIdx.x;
      bool inb = f < nf4;
      float4 v4 = make_float4(0.f, 0.f, 0.f, 0.f);
      if (inb) v4 = src4[f];
      int e0 = f * 4;
      emit(e0+0, v4.x, inb && (mapbits(v4.x) >= T));
      emit(e0+1, v4.y, inb && (mapbits(v4.y) >= T));
      emit(e0+2, v4.z, inb && (mapbits(v4.z) >= T));
      emit(e0+3, v4.w, inb && (mapbits(v4.w) >= T));
    }
  } else {
    int base = chunk * 4096;
    #pragma unroll
    for (int j = 0; j < 16; j++) {
      int e = base + j*256 + threadIdx.x;
      float v = 0.0f;
      bool inb = (e < HWA[4]);
      if (inb) v = src[e];
      emit(e, v, inb && (mapbits(v) >= T));
    }
  }
  __syncthreads();
  if (threadIdx.x == 0) gbase = atomicAdd(&cnt[pair], lc);  // one global atomic/block
  __syncthreads();
  unsigned nsel = lc, gb = gbase;
  float Wi = (float)(*in.iw), Hi = (float)(*in.ih);
  int Wl = LW[lvl];
  float st = (float)LSTR[lvl];
  const float* rg = in.reg[lvl] + (size_t)img * 4 * HWA[lvl];  // 12*H*W
  for (unsigned t = threadIdx.x; t < nsel; t += 256) {
    unsigned p = gb + t;
    if (p < CAP) {
      unsigned idx = lbuf[t];
      ckey[(size_t)pair*CAP + p] = lkey[t];                 // coalesced
      // mmdet DeltaXYWH decode, clipped — bit-identical pipeline
      int a = (int)(idx % 3u);
      int r = (int)(idx / 3u);
      int x = r % Wl, y = r / Wl;
      float dx = rg[(a*4+0)*hw + r];
      float dy = rg[(a*4+1)*hw + r];
      float dwv = rg[(a*4+2)*hw + r];
      float dhv = rg[(a*4+3)*hw + r];
      float ratio = (a==0) ? 0.5f : (a==1) ? 1.0f : 2.0f;
      float hr = sqrtf(ratio);
      float wr = 1.0f / hr;
      float wsz = st * wr * 8.0f;
      float hsz = st * hr * 8.0f;
      float xs = (float)x * st, ys = (float)y * st;
      float x1 = xs - wsz*0.5f, x2 = xs + wsz*0.5f;
      float y1 = ys - hsz*0.5f, y2 = ys + hsz*0.5f;
      float px = (x1 + x2) * 0.5f, py = (y1 + y2) * 0.5f;
      float pw = x2 - x1,          ph = y2 - y1;
      const float MR = 4.135166556742356f;
      dwv = fminf(fmaxf(dwv, -MR), MR);
      dhv = fminf(fmaxf(dhv, -MR), MR);
      float gx = px + pw*dx, gy = py + ph*dy;
      float gw = pw * (float)exp((double)dwv);   // correctly-rounded f32 exp
      float gh = ph * (float)exp((double)dhv);
      float4 bb;
      bb.x = fminf(fmaxf(gx - gw*0.5f, 0.0f), Wi);
      bb.y = fminf(fmaxf(gy - gh*0.5f, 0.0f), Hi);
      bb.z = fminf(fmaxf(gx + gw*0.5f, 0.0f), Wi);
      bb.w = fminf(fmaxf(gy + gh*0.5f, 0.0f), Hi);
      cbox[(size_t)pair*CAP + p] = bb;
    }
  }
}

// ---- K4: sliced rank accumulate + FUSED selection (last-block). Grid
// (tile, slice, pair): each block compares its 256 mykeys against one 256-key
// LDS slice, atomicAdds partial ranks; the last of the 576 blocks per pair
// applies rank<KSEL selection (coalesced reads, scattered stores). ----
__global__ void __launch_bounds__(256) k_racc(const unsigned* __restrict__ cntA,
                       const unsigned long long* __restrict__ ckey,
                       unsigned* __restrict__ rnk, unsigned* __restrict__ arrr,
                       const float4* __restrict__ cbox,
                       unsigned long long* __restrict__ sel_key,
                       float* __restrict__ sel_box) {
  int pair = blockIdx.z;
  int img = pair / NLVL, lvl = pair % NLVL;
  int c = min((int)cntA[pair], CAP);
  int tile = blockIdx.x, slice = blockIdx.y;
  const unsigned long long* kp = ckey + (size_t)pair*CAP;
  if (tile*256 < c && slice*256 < c) {       // block-uniform guard (barrier-safe)
    __shared__ unsigned long long sk[256];
    int g = slice*256 + threadIdx.x;
    sk[threadIdx.x] = (g < c) ? kp[g] : 0ull;   // pad 0: never > any real key
    __syncthreads();
    int jj = tile*256 + threadIdx.x;
    unsigned long long mykey = kp[min(jj, c-1)];
    const ulonglong2* sk2 = (const ulonglong2*)sk;
    int r0 = 0, r1 = 0, r2 = 0, r3 = 0;
    #pragma unroll 8
    for (int j2 = 0; j2 < 128; j2 += 2) {       // uniform ds_read_b128 broadcast
      ulonglong2 a = sk2[j2];
      ulonglong2 b = sk2[j2+1];
      r0 += (a.x > mykey) ? 1 : 0;
      r1 += (a.y > mykey) ? 1 : 0;
      r2 += (b.x > mykey) ? 1 : 0;
      r3 += (b.y > mykey) ? 1 : 0;
    }
    int rk = (r0 + r1) + (r2 + r3);
    if (jj < c && rk) atomicAdd(&rnk[pair*CAP + jj], (unsigned)rk);
  }
  // ---- fused rsel: last block of this pair applies the selection ----
  __threadfence();                       // release
  __shared__ unsigned soldr;
  if (threadIdx.x == 0) soldr = atomicAdd(&arrr[pair], 1u);
  __syncthreads();
  if (soldr != 575u) return;             // 24*24 blocks per pair
  __threadfence();                       // acquire
  for (int t0 = (int)threadIdx.x; t0 < c; t0 += 256) {
    int rk = (int)rnk[pair*CAP + t0];
    if (rk < KSEL[lvl]) {
      int slot = img*MTOT + SOFF[lvl] + rk;
      sel_key[slot] = kp[t0];
      ((float4*)sel_box)[slot] = cbox[(size_t)pair*CAP + t0];
    }
  }
}

// ---- K6: NMS mask build (64 rows x 128 cols per wave, f32 bracket + exact f64
// redo) + FUSED greedy NMS + prefix counts (last-block, 256-thread redesign:
// 8 rows/thread, mask words read once from L2; wave-0 register Jacobi). ----
__global__ void __launch_bounds__(256) k_masks(const float* __restrict__ sel_box,
                        unsigned long long* __restrict__ maskbuf,
                        unsigned* __restrict__ arrm,
                        unsigned long long* __restrict__ keep,
                        int* __restrict__ pkc) {
  int pair = blockIdx.y; int lvl = pair % NLVL; int img = pair / NLVL;
  int n = KSEL[lvl];
  int nw = (n + 63) >> 6;
  int nwc2 = (nw + 1) >> 1;
  int wv = threadIdx.x >> 6;
  int lane = threadIdx.x & 63;
  int t = blockIdx.x * 4 + wv;           // flat tile id over (rb, jw2)
  __shared__ float4 sbox[4][64];
  __shared__ float  sarea[4][64];
  if (t < NT2[lvl]) {                    // guarded (no return: all threads must arrive)
    int rb = 0, cum = 0;
    while (cum + (nwc2 - (rb >> 1)) <= t) { cum += nwc2 - (rb >> 1); rb++; }
    int jw2 = (rb >> 1) + (t - cum);
    int jw0 = 2*jw2, jw1 = jw0 + 1;
    const float4* boxes = ((const float4*)sel_box) + img*MTOT + SOFF[lvl];
    float off = (float)lvl * 4096.0f;
    int c0 = jw0*64 + lane, c1 = c0 + 64;
    float b0x,b0y,b0z,b0w,a0, b1x,b1y,b1z,b1w,a1;
    if (c0 < n) {
      float4 b = boxes[c0];
      b0x = b.x + off; b0y = b.y + off; b0z = b.z + off; b0w = b.w + off;
      a0 = (b0z - b0x) * (b0w - b0y);
    } else { b0x=b0y=b0z=b0w=3.0e8f; a0=0.0f; }
    if (c1 < n) {
      float4 b = boxes[c1];
      b1x = b.x + off; b1y = b.y + off; b1z = b.z + off; b1w = b.w + off;
      a1 = (b1z - b1x) * (b1w - b1y);
    } else { b1x=b1y=b1z=b1w=3.0e8f; a1=0.0f; }
    int row0 = rb*64;
    {
      float4 bi0 = boxes[min(row0 + lane, n-1)];
      bi0.x += off; bi0.y += off; bi0.z += off; bi0.w += off;
      sbox[wv][lane] = bi0;
      sarea[wv][lane] = (bi0.z - bi0.x) * (bi0.w - bi0.y);
    }
    bool z0 = (jw0 < rb);                  // word0 entirely below diagonal
    bool d0 = (jw0 == rb), d1 = (jw1 == rb);
    // bracket constants: 0.7f=0x1.666666p-1; c_lo=pred, c_hi=succ^2.
    const float CHI = 0x1.66666ap-1f;      // 0x3F333335
    const float CLO = 0x1.666664p-1f;      // 0x3F333332
    unsigned long long acc0 = 0ull, acc1 = 0ull, unc = 0ull;
    #pragma unroll 16
    for (int r = 0; r < 64; r++) {
      float4 bi = sbox[wv][r];             // LDS broadcast (uniform address)
      float ai = sarea[wv][r];
      float xx1 = fmaxf(bi.x, b0x), yy1 = fmaxf(bi.y, b0y);
      float xx2 = fminf(bi.z, b0z), yy2 = fminf(bi.w, b0w);
      float iw_ = fmaxf(xx2 - xx1, 0.0f), ih_ = fmaxf(yy2 - yy1, 0.0f);
      float in0 = iw_ * ih_;
      float u0 = fmaxf((ai + a0) - in0, 1e-6f);
      float xc1 = fmaxf(bi.x, b1x), yc1 = fmaxf(bi.y, b1y);
      float xc2 = fminf(bi.z, b1z), yc2 = fminf(bi.w, b1w);
      float jw_ = fmaxf(xc2 - xc1, 0.0f), jh_ = fmaxf(yc2 - yc1, 0.0f);
      float in1 = jw_ * jh_;
      float u1 = fmaxf((ai + a1) - in1, 1e-6f);
      unsigned long long h0 = __ballot(in0 >= CHI * u0);
      unsigned long long l0 = __ballot(in0 >= CLO * u0);
      unsigned long long h1 = __ballot(in1 >= CHI * u1);
      unsigned long long l1 = __ballot(in1 >= CLO * u1);
      unc |= (h0 ^ l0) | (h1 ^ l1);
      unsigned long long dm = ~((2ull << r) - 1ull);   // strictly-upper within word
      unsigned long long m0 = z0 ? 0ull : (d0 ? (h0 & dm) : h0);
      unsigned long long m1 = d1 ? (h1 & dm) : h1;
      if (lane == r) { acc0 = m0; acc1 = m1; }
    }
    if (unc) {                             // rare: exact f64 redo of the whole tile
      const double Md = 0.70000001788139343261718750;  // (0.7f + succ(0.7f))/2 exact
      acc0 = 0ull; acc1 = 0ull;
      #pragma unroll 1
      for (int r = 0; r < 64; r++) {
        float4 bi = sbox[wv][r];
        float ai = sarea[wv][r];
        float xx1 = fmaxf(bi.x, b0x), yy1 = fmaxf(bi.y, b0y);
        float xx2 = fminf(bi.z, b0z), yy2 = fminf(bi.w, b0w);
        float iw_ = fmaxf(xx2 - xx1, 0.0f), ih_ = fmaxf(yy2 - yy1, 0.0f);
        float in0 = iw_ * ih_;
        float u0 = fmaxf((ai + a0) - in0, 1e-6f);
        float xc1 = fmaxf(bi.x, b1x), yc1 = fmaxf(bi.y, b1y);
        float xc2 = fminf(bi.z, b1z), yc2 = fminf(bi.w, b1w);
        float jw_ = fmaxf(xc2 - xc1, 0.0f), jh_ = fmaxf(yc2 - yc1, 0.0f);
        float in1 = jw_ * jh_;
        float u1 = fmaxf((ai + a1) - in1, 1e-6f);
        unsigned long long w0 = __ballot((double)in0 >= Md * (double)u0);
        unsigned long long w1 = __ballot((double)in1 >= Md * (double)u1);
        unsigned long long dm = ~((2ull << r) - 1ull);
        unsigned long long m0 = z0 ? 0ull : (d0 ? (w0 & dm) : w0);
        unsigned long long m1 = d1 ? (w1 & dm) : w1;
        if (lane == r) { acc0 = m0; acc1 = m1; }
      }
    }
    int row = row0 + lane;
    if (row < n) {
      unsigned long long* dst = maskbuf + (size_t)pair*2000*MASK_W + (size_t)row*MASK_W + jw0;
      if (z0) {
        dst[1] = acc1;                     // only the diagonal word exists
      } else {
        ulonglong2 v; v.x = acc0; v.y = acc1;
        *((ulonglong2*)dst) = v;           // 16B-aligned (jw0 even)
      }
    }
  }
  // ---- fused NMS: last block of this pair runs exact greedy NMS + prefix ----
  __threadfence();                       // release mask writes
  __shared__ unsigned soldm;
  if (threadIdx.x == 0) soldm = atomicAdd(&arrm[pair], 1u);
  __syncthreads();
  if (soldm != 67u) return;              // 68 blocks per pair
  __threadfence();                       // acquire: see all pairs' tiles
  {
    const unsigned long long* mrow = maskbuf + (size_t)pair*2000*MASK_W;
    int tid = threadIdx.x;
    int w  = tid & 31;                   // word owned (0..31)
    int rg = tid >> 5;                   // row group (0..7): rows rg*8 .. rg*8+7
    __shared__ unsigned long long rem2[32];
    __shared__ unsigned long long diag2[64];
    __shared__ unsigned long long skw2[32];
    __shared__ unsigned long long sSk2;
    __shared__ int lcnt2[64];
    if (tid < 32) { rem2[tid] = 0ull; skw2[tid] = 0ull; }
    __syncthreads();
    for (int k = 0; k < nw; k++) {
      if (w == k) {                      // 8 threads stage the 64 diag words
        #pragma unroll
        for (int j = 0; j < 8; j++) {
          int row = min(64*k + rg*8 + j, n-1);
          diag2[rg*8 + j] = mrow[(size_t)row*MASK_W + k];
        }
      }
      __syncthreads();
      if (tid < 64) {                    // wave 0: in-block register Jacobi
        int row = 64*k + tid;
        bool valid = row < n;
        unsigned long long D = valid ? diag2[tid] : 0ull;   // already strictly upper
        unsigned long long rk = rem2[k];
        unsigned long long S = rk;
        for (int it = 0; it < 64; it++) {
          bool kept = valid && !((S >> tid) & 1ull);
          unsigned long long c = kept ? D : 0ull;
          #pragma unroll
          for (int m = 1; m < 64; m <<= 1) {               // wave-wide OR
            unsigned lo = (unsigned)__shfl_xor((int)(unsigned)(c & 0xffffffffull), m, 64);
            unsigned hi = (unsigned)__shfl_xor((int)(unsigned)(c >> 32), m, 64);
            c |= ((unsigned long long)hi << 32) | (unsigned long long)lo;
          }
          unsigned long long Snew = rk | c;                // uniform across wave
          if (Snew == S) break;                            // fixpoint (<= depth iters)
          S = Snew;
        }
        if (tid == 0) {
          sSk2 = S;
          int nb = n - 64*k;
          unsigned long long vm = (nb >= 64) ? ~0ull : ((1ull << nb) - 1ull);
          unsigned long long kw = (~S) & vm;
          skw2[k] = kw;
          keep[(size_t)pair*MASK_W + k] = kw;
        }
      }
      __syncthreads();
      if (w > k) {                       // accumulate alive rows into later words
        unsigned long long Sk = sSk2;
        unsigned long long m = 0ull;
        #pragma unroll
        for (int j = 0; j < 8; j++) {
          int rr = rg*8 + j; int row = 64*k + rr;
          if (row < n && !((Sk >> rr) & 1ull))
            m |= mrow[(size_t)row*MASK_W + w];
        }
        if (m) atomicOr(&rem2[w], m);
      }
      __syncthreads();
    }
    // ---- fused prefix counts; wave 0, skw2 already masked ----
    if (tid < 64) {
      int lane2 = tid;
      unsigned long long kw = (lane2 < nw) ? skw2[lane2] : 0ull;
      lcnt2[lane2] = __popcll(kw);       // wave-synchronous LDS (no barrier needed)
      int pre = 0;
      for (int t2 = 0; t2 < lane2; t2++) pre += lcnt2[t2];
      for (int b = 0; b < 64; b++) {
        int p = lane2*64 + b;
        if (p < n) {
          pre += (int)((kw >> b) & 1ull);
          pkc[pair*2048 + p] = pre;
        }
      }
    }
  }
}

// ---- K8: rank kept boxes via per-level prefix counts + 4 binary searches ----
__global__ void __launch_bounds__(256) k_out2(const unsigned long long* __restrict__ sel_key,
                      const float* __restrict__ sel_box,
                      const unsigned long long* __restrict__ keep,
                      const int* __restrict__ pkc,
                      float* __restrict__ out) {
  int img = blockIdx.y;
  int pos = blockIdx.x*256 + threadIdx.x;
  if (pos >= MTOT) return;
  int lvl = pos<2000?0 : pos<4000?1 : pos<6000?2 : pos<8000?3 : 4;
  int local = pos - SOFF[lvl];
  int pair = img*NLVL + lvl;
  unsigned long long kw = keep[(size_t)pair*MASK_W + (local >> 6)];
  if (!((kw >> (local & 63)) & 1ull)) return;
  unsigned long long mykey = sel_key[img*MTOT + pos];
  int rank = pkc[pair*2048 + local] - 1;    // kept before me within my level
  #pragma unroll
  for (int l2 = 0; l2 < NLVL; l2++) {
    if (l2 == lvl) continue;
    const unsigned long long* A = sel_key + img*MTOT + SOFF[l2];
    int lo = 0, hi = KSEL[l2];
    while (lo < hi) {
      int mid = (lo + hi) >> 1;
      if (A[mid] > mykey) lo = mid + 1; else hi = mid;
    }
    if (lo > 0) rank += pkc[(img*NLVL + l2)*2048 + lo - 1];
  }
  if (rank < OUTK) {
    ((float4*)out)[img*OUTK + rank] = ((const float4*)sel_box)[img*MTOT + pos];
    out[NIMG*OUTK*4 + img*OUTK + rank] = __uint_as_float((unsigned)(mykey >> 21));
  }
}

extern "C" void kernel_launch(void* const* d_in, const int* in_sizes, int n_in,
                              void* d_out, int out_size, void* d_ws, size_t ws_size,
                              hipStream_t stream) {
  Ins in;
  // setup_inputs dict order: cls_0, reg_0, cls_1, reg_1, ..., cls_4, reg_4, image_h, image_w
  for (int l = 0; l < 5; l++) {
    in.cls[l] = (const float*)d_in[2*l];
    in.reg[l] = (const float*)d_in[2*l + 1];
  }
  in.ih = (const int*)d_in[10];
  in.iw = (const int*)d_in[11];

  char* ws = (char*)d_ws;
  unsigned* hist              = (unsigned*)(ws + OFF_HIST);
  int* pkc                    = (int*)(ws + OFF_PKC);          // aliases hist (dead after hist+scan)
  unsigned* cnt               = (unsigned*)(ws + OFF_CNT);
  unsigned* thr               = (unsigned*)(ws + OFF_THR);
  unsigned* arrh              = (unsigned*)(ws + OFF_ARRH);
  unsigned* arrr              = (unsigned*)(ws + OFF_ARRR);
  unsigned* arrm              = (unsigned*)(ws + OFF_ARRM);
  unsigned* rnk               = (unsigned*)(ws + OFF_RNK);
  unsigned long long* sel_key = (unsigned long long*)(ws + OFF_SELKEY);
  float* sel_box              = (float*)(ws + OFF_SELBOX);
  unsigned long long* maskbuf = (unsigned long long*)(ws + OFF_MASK);
  unsigned long long* ckey    = (unsigned long long*)(ws + OFF_CKEY);  // aliases maskbuf (dead before k_masks)
  float4* cbox                = (float4*)(ws + OFF_CBOX);              // aliases maskbuf (dead before k_masks)
  unsigned long long* keep    = (unsigned long long*)(ws + OFF_KEEP);
  float* out                  = (float*)d_out;

  // 6 launches (was 10): launch-gap overhead was the dominant unprofiled cost.
  k_zero   <<<256, 256, 0, stream>>>((float*)ws, out);
  k_hist   <<<NIMG*BLK_PER_IMG, 256, 0, stream>>>(in, hist, arrh, thr);
  k_compact<<<NIMG*BLK_PER_IMG, 256, 0, stream>>>(in, thr, cnt, ckey, cbox);
  k_racc   <<<dim3(CAP/256, CAP/256, NPAIR), 256, 0, stream>>>(cnt, ckey, rnk, arrr, cbox, sel_key, sel_box);
  k_masks  <<<dim3(68, NPAIR), 256, 0, stream>>>(sel_box, maskbuf, arrm, keep, pkc);
  k_out2   <<<dim3((MTOT + 255)/256, NIMG), 256, 0, stream>>>(sel_key, sel_box, keep, pkc, out);
}

// Round 8
// 248.266 us; speedup vs baseline: 8.6121x; 8.6121x over previous
//
#include <hip/hip_runtime.h>
#include <cmath>

// Match XLA/numpy non-fused mul+add rounding everywhere (IoU / decode bit-faithfulness).
#pragma clang fp contract(off)

namespace {
constexpr int NIMG = 8;
constexpr int NLVL = 5;
constexpr int LH[5]   = {208,104,52,26,13};
constexpr int LW[5]   = {336,168,84,42,21};
constexpr int LSTR[5] = {4,8,16,32,64};
constexpr int HWA[5]  = {209664,52416,13104,3276,819};
constexpr int KSEL[5] = {2000,2000,2000,2000,819};
constexpr int SOFF[5] = {0,2000,4000,6000,8000};
constexpr int MTOT    = 8819;
constexpr int CAP     = 6144;          // per-(img,lvl) candidate cap (expect <= ~2600)
constexpr int NPAIR   = NIMG*NLVL;     // 40
constexpr int CCUM[5] = {52,65,69,70,71};  // cumulative ceil(HWA/4096) per level
constexpr int BLK_PER_IMG = 71;
constexpr int MASK_W  = 32;            // u64 words per NMS mask row (covers 2048 cols)
constexpr int OUTK    = 1000;
// 128-col mask tiles: rb in [0,nw), jw2 in [rb>>1, ceil(nw/2)); counts:
constexpr int NT2[5]  = {272,272,272,272,55};

// workspace byte offsets (all 16B-aligned where needed)
constexpr size_t OFF_HIST   = 0;              // 40*4096*4      = 655360
constexpr size_t OFF_PKC    = 0;              // 40*2048*4 = 327680, aliases hist (dead after k_compact)
constexpr size_t OFF_CNT    = 655360;         // 40*4           = 160
constexpr size_t OFF_RNK    = 655872;         // 40*6144*4      = 983040  -> 1638912 (zeroed)
constexpr size_t ZERO_BYTES = 1638912;        // memset range (hist+cnt+rnk)
constexpr size_t OFF_SELKEY = 1921120;        // 8*8819*8       = 564416  -> 2485536
constexpr size_t OFF_SELBOX = 2767744;        // 8*8819*16      = 1128832 -> 3896576
constexpr size_t OFF_MASK   = 3896576;        // 40*2000*32*8   = 20480000-> 24376576
constexpr size_t OFF_CKEY   = OFF_MASK;       // 40*6144*8 = 1.97MB aliases maskbuf (dead by k_masks)
constexpr size_t OFF_CBOX   = OFF_MASK + 2097152; // 40*6144*16 = 3.93MB, aliases maskbuf (dead by k_masks)
constexpr size_t OFF_KEEP   = 24376576;       // 40*32*8        = 10240   -> 24386816
}

struct Ins {
  const float* cls[5];
  const float* reg[5];
  const int* ih;
  const int* iw;
};

__device__ __forceinline__ void decode_block(int b, int& img, int& lvl, int& chunk) {
  img = b / BLK_PER_IMG;
  int rb = b - img*BLK_PER_IMG;
  if      (rb < CCUM[0]) { lvl=0; chunk=rb; }
  else if (rb < CCUM[1]) { lvl=1; chunk=rb-CCUM[0]; }
  else if (rb < CCUM[2]) { lvl=2; chunk=rb-CCUM[1]; }
  else if (rb < CCUM[3]) { lvl=3; chunk=rb-CCUM[2]; }
  else                   { lvl=4; chunk=0; }
}

// order-preserving float->u32 map (total order over floats)
__device__ __forceinline__ unsigned mapbits(float x) {
  unsigned u = __float_as_uint(x);
  return u ^ (unsigned)(((int)u >> 31) | (int)0x80000000);
}

// fp32 sigmoid with correctly-rounded exp step: matches 1/(1+exp_f32(-x)) pipeline
__device__ __forceinline__ float sigmoid_ref(float x) {
  float e = (float)exp(-(double)x);   // correctly-rounded f32 exp(-x)
  return 1.0f / (1.0f + e);           // exact-IEEE add + div
}

// ---- K1: per-(img,lvl) 12-bit histogram (float4 loads) + FUSED d_out zeroing
// (out untouched until k_out2; kernel boundaries order it — no sync needed) ----
__global__ void k_hist(Ins in, unsigned* __restrict__ hist, float4* __restrict__ outz) {
  {  // grid-stride zero of the 160KB output buffer (replaces one memset launch)
    const int NOUT = NIMG*OUTK*5*4/16;   // 10000 float4
    float4 z = make_float4(0.f,0.f,0.f,0.f);
    int i0 = blockIdx.x*256 + threadIdx.x, stride = gridDim.x*256;
    for (int j = i0; j < NOUT; j += stride) outz[j] = z;
  }
  int img, lvl, chunk; decode_block(blockIdx.x, img, lvl, chunk);
  __shared__ unsigned lh[4096];
  for (int i = threadIdx.x; i < 4096; i += 256) lh[i] = 0;
  __syncthreads();
  const float* src = in.cls[lvl] + (size_t)img * HWA[lvl];
  if (lvl != 4) {                        // HWA divisible by 4, 16B-aligned per image
    const float4* src4 = (const float4*)src;
    int nf4 = HWA[lvl] >> 2;
    int base4 = chunk * 1024;
    #pragma unroll
    for (int j = 0; j < 4; j++) {
      int f = base4 + j*256 + threadIdx.x;
      if (f < nf4) {
        float4 v = src4[f];
        atomicAdd(&lh[mapbits(v.x) >> 20], 1u);
        atomicAdd(&lh[mapbits(v.y) >> 20], 1u);
        atomicAdd(&lh[mapbits(v.z) >> 20], 1u);
        atomicAdd(&lh[mapbits(v.w) >> 20], 1u);
      }
    }
  } else {                               // lvl 4: 819 elements, misaligned — scalar
    int base = chunk * 4096;
    #pragma unroll
    for (int j = 0; j < 16; j++) {
      int e = base + j*256 + threadIdx.x;
      if (e < HWA[4]) atomicAdd(&lh[mapbits(src[e]) >> 20], 1u);
    }
  }
  __syncthreads();
  unsigned* gh = hist + (img*NLVL + lvl) * 4096;
  for (int i = threadIdx.x; i < 4096; i += 256)
    if (lh[i]) atomicAdd(&gh[i], lh[i]);
}

// ---- K3: FUSED threshold scan (redundant per-block, from completed hist) +
// compact candidates + sort keys + box decode. The per-block scan re-reads the
// L2-hot histogram across a kernel boundary — no fences/counters (the R7
// last-block+threadfence pattern cost ~0.5us/block in L2 writebacks). ----
__global__ void __launch_bounds__(256) k_compact(Ins in, const unsigned* __restrict__ hist,
                          unsigned* __restrict__ cnt,
                          unsigned long long* __restrict__ ckey,
                          float4* __restrict__ cbox) {
  int img, lvl, chunk; decode_block(blockIdx.x, img, lvl, chunk);
  int pair = img*NLVL + lvl;
  // --- threshold scan prologue (was k_scan; identical arithmetic) ---
  __shared__ unsigned part[256];
  __shared__ unsigned sT;
  const unsigned* gh = hist + (size_t)pair * 4096;
  {
    unsigned s = 0;
    #pragma unroll
    for (int i = 0; i < 16; i++) s += gh[threadIdx.x*16 + i];
    part[threadIdx.x] = s;
  }
  __syncthreads();
  if (threadIdx.x == 0) {
    unsigned k = (unsigned)KSEL[lvl];
    unsigned cum = 0, T = 0;
    for (int t = 255; t >= 0; t--) {
      if (cum + part[t] >= k) {
        unsigned edge = 0;
        for (int b = t*16 + 15; b >= t*16; b--) {
          cum += gh[b];
          if (cum >= k) { edge = (unsigned)b; break; }
        }
        T = edge << 20;
        break;
      }
      cum += part[t];
    }
    sT = T;
  }
  __syncthreads();
  unsigned T = sT;

  const float* src = in.cls[lvl] + (size_t)img * HWA[lvl];
  int hw = LH[lvl] * LW[lvl];
  int lid = threadIdx.x & 63;
  __shared__ unsigned lbuf[4096];            // block covers <=4096 elements
  __shared__ unsigned long long lkey[4096];  // 32KB key staging
  __shared__ unsigned lc, gbase;
  if (threadIdx.x == 0) lc = 0;
  __syncthreads();

  auto emit = [&](int e, float v, bool sel) {
    unsigned long long mask = __ballot(sel);
    if (mask != 0ull) {
      int leader = __ffsll((long long)mask) - 1;
      unsigned wb = 0;
      if (lid == leader) wb = atomicAdd(&lc, (unsigned)__popcll(mask));  // LDS atomic
      wb = (unsigned)__shfl((int)wb, leader, 64);
      if (sel) {
        unsigned p = wb + (unsigned)__popcll(mask & ((1ull << lid) - 1ull));
        int a = e / hw;            // NCHW: e = a*hw + r
        int r = e - a*hw;
        unsigned idx = (unsigned)(r*3 + a);  // score-space idx
        lbuf[p] = idx;
        float s = sigmoid_ref(v);            // dp-exp on selected lanes only
        unsigned pack = ((unsigned)lvl << 18) | idx;   // < 2^21
        lkey[p] = ((unsigned long long)__float_as_uint(s) << 21)
                | (unsigned long long)(0x1FFFFFu - pack);  // desc score, asc (lvl,idx)
      }
    }
  };

  if (lvl != 4) {
    const float4* src4 = (const float4*)src;
    int nf4 = HWA[lvl] >> 2;
    int base4 = chunk * 1024;
    #pragma unroll
    for (int j = 0; j < 4; j++) {
      int f = base4 + j*256 + threadIdx.x;
      bool inb = f < nf4;
      float4 v4 = make_float4(0.f, 0.f, 0.f, 0.f);
      if (inb) v4 = src4[f];
      int e0 = f * 4;
      emit(e0+0, v4.x, inb && (mapbits(v4.x) >= T));
      emit(e0+1, v4.y, inb && (mapbits(v4.y) >= T));
      emit(e0+2, v4.z, inb && (mapbits(v4.z) >= T));
      emit(e0+3, v4.w, inb && (mapbits(v4.w) >= T));
    }
  } else {
    int base = chunk * 4096;
    #pragma unroll
    for (int j = 0; j < 16; j++) {
      int e = base + j*256 + threadIdx.x;
      float v = 0.0f;
      bool inb = (e < HWA[4]);
      if (inb) v = src[e];
      emit(e, v, inb && (mapbits(v) >= T));
    }
  }
  __syncthreads();
  if (threadIdx.x == 0) gbase = atomicAdd(&cnt[pair], lc);  // one global atomic/block
  __syncthreads();
  unsigned nsel = lc, gb = gbase;
  float Wi = (float)(*in.iw), Hi = (float)(*in.ih);
  int Wl = LW[lvl];
  float st = (float)LSTR[lvl];
  const float* rg = in.reg[lvl] + (size_t)img * 4 * HWA[lvl];  // 12*H*W
  for (unsigned t = threadIdx.x; t < nsel; t += 256) {
    unsigned p = gb + t;
    if (p < CAP) {
      unsigned idx = lbuf[t];
      ckey[(size_t)pair*CAP + p] = lkey[t];                 // coalesced
      // mmdet DeltaXYWH decode, clipped — bit-identical pipeline
      int a = (int)(idx % 3u);
      int r = (int)(idx / 3u);
      int x = r % Wl, y = r / Wl;
      float dx = rg[(a*4+0)*hw + r];
      float dy = rg[(a*4+1)*hw + r];
      float dwv = rg[(a*4+2)*hw + r];
      float dhv = rg[(a*4+3)*hw + r];
      float ratio = (a==0) ? 0.5f : (a==1) ? 1.0f : 2.0f;
      float hr = sqrtf(ratio);
      float wr = 1.0f / hr;
      float wsz = st * wr * 8.0f;
      float hsz = st * hr * 8.0f;
      float xs = (float)x * st, ys = (float)y * st;
      float x1 = xs - wsz*0.5f, x2 = xs + wsz*0.5f;
      float y1 = ys - hsz*0.5f, y2 = ys + hsz*0.5f;
      float px = (x1 + x2) * 0.5f, py = (y1 + y2) * 0.5f;
      float pw = x2 - x1,          ph = y2 - y1;
      const float MR = 4.135166556742356f;
      dwv = fminf(fmaxf(dwv, -MR), MR);
      dhv = fminf(fmaxf(dhv, -MR), MR);
      float gx = px + pw*dx, gy = py + ph*dy;
      float gw = pw * (float)exp((double)dwv);   // correctly-rounded f32 exp
      float gh2 = ph * (float)exp((double)dhv);
      float4 bb;
      bb.x = fminf(fmaxf(gx - gw*0.5f, 0.0f), Wi);
      bb.y = fminf(fmaxf(gy - gh2*0.5f, 0.0f), Hi);
      bb.z = fminf(fmaxf(gx + gw*0.5f, 0.0f), Wi);
      bb.w = fminf(fmaxf(gy + gh2*0.5f, 0.0f), Hi);
      cbox[(size_t)pair*CAP + p] = bb;
    }
  }
}

// ---- K4a: sliced rank accumulate. Grid (tile, slice, pair): each block
// compares its 256 mykeys against one 256-key LDS slice and atomicAdds the
// partial rank (~4800 active blocks — fixes the old 9%-occupancy scan). ----
__global__ void __launch_bounds__(256) k_racc(const unsigned* __restrict__ cntA,
                       const unsigned long long* __restrict__ ckey,
                       unsigned* __restrict__ rnk) {
  int pair = blockIdx.z;
  int c = min((int)cntA[pair], CAP);
  int tile = blockIdx.x, slice = blockIdx.y;
  if (tile*256 >= c || slice*256 >= c) return;
  const unsigned long long* kp = ckey + (size_t)pair*CAP;
  __shared__ unsigned long long sk[256];
  int g = slice*256 + threadIdx.x;
  sk[threadIdx.x] = (g < c) ? kp[g] : 0ull;   // pad 0: never > any real key
  __syncthreads();
  int jj = tile*256 + threadIdx.x;
  unsigned long long mykey = kp[min(jj, c-1)];
  const ulonglong2* sk2 = (const ulonglong2*)sk;
  int r0 = 0, r1 = 0, r2 = 0, r3 = 0;
  #pragma unroll 8
  for (int j2 = 0; j2 < 128; j2 += 2) {       // uniform ds_read_b128 broadcast
    ulonglong2 a = sk2[j2];
    ulonglong2 b = sk2[j2+1];
    r0 += (a.x > mykey) ? 1 : 0;
    r1 += (a.y > mykey) ? 1 : 0;
    r2 += (b.x > mykey) ? 1 : 0;
    r3 += (b.y > mykey) ? 1 : 0;
  }
  int rk = (r0 + r1) + (r2 + r3);
  if (jj < c && rk) atomicAdd(&rnk[pair*CAP + jj], (unsigned)rk);
}

// ---- K4b: apply selection from final ranks (coalesced) ----
__global__ void __launch_bounds__(256) k_rsel(const unsigned* __restrict__ cntA,
                       const unsigned long long* __restrict__ ckey,
                       const float4* __restrict__ cbox,
                       const unsigned* __restrict__ rnk,
                       unsigned long long* __restrict__ sel_key,
                       float* __restrict__ sel_box) {
  int pair = blockIdx.y; int tile = blockIdx.x;
  int img = pair / NLVL, lvl = pair % NLVL;
  int c = min((int)cntA[pair], CAP);
  int jj = tile*256 + threadIdx.x;
  if (jj >= c) return;
  int rk = (int)rnk[pair*CAP + jj];
  if (rk < KSEL[lvl]) {
    int slot = img*MTOT + SOFF[lvl] + rk;
    sel_key[slot] = ckey[(size_t)pair*CAP + jj];
    ((float4*)sel_box)[slot] = cbox[(size_t)pair*CAP + jj];
  }
}

// ---- K6: NMS suppression-mask build — 64 rows x 128 cols per wave ----
// 2 cols/lane, row area precomputed into LDS, f32 bracket compare (c_lo/c_hi
// around Md) with exact-f64 tile redo when inconclusive (exact always).
__global__ void __launch_bounds__(256) k_masks(const float* __restrict__ sel_box,
                        unsigned long long* __restrict__ maskbuf) {
  int pair = blockIdx.y; int lvl = pair % NLVL; int img = pair / NLVL;
  int n = KSEL[lvl];
  int nw = (n + 63) >> 6;
  int nwc2 = (nw + 1) >> 1;
  int wv = threadIdx.x >> 6;
  int lane = threadIdx.x & 63;
  int t = blockIdx.x * 4 + wv;           // flat tile id over (rb, jw2)
  if (t >= NT2[lvl]) return;             // wave-level exit (no barriers used)
  int rb = 0, cum = 0;
  while (cum + (nwc2 - (rb >> 1)) <= t) { cum += nwc2 - (rb >> 1); rb++; }
  int jw2 = (rb >> 1) + (t - cum);
  int jw0 = 2*jw2, jw1 = jw0 + 1;
  const float4* boxes = ((const float4*)sel_box) + img*MTOT + SOFF[lvl];
  float off = (float)lvl * 4096.0f;
  // two columns per lane: c0 = jw0*64+lane, c1 = c0+64
  int c0 = jw0*64 + lane, c1 = c0 + 64;
  float b0x,b0y,b0z,b0w,a0, b1x,b1y,b1z,b1w,a1;
  if (c0 < n) {
    float4 b = boxes[c0];
    b0x = b.x + off; b0y = b.y + off; b0z = b.z + off; b0w = b.w + off;
    a0 = (b0z - b0x) * (b0w - b0y);
  } else { b0x=b0y=b0z=b0w=3.0e8f; a0=0.0f; }
  if (c1 < n) {
    float4 b = boxes[c1];
    b1x = b.x + off; b1y = b.y + off; b1z = b.z + off; b1w = b.w + off;
    a1 = (b1z - b1x) * (b1w - b1y);
  } else { b1x=b1y=b1z=b1w=3.0e8f; a1=0.0f; }
  __shared__ float4 sbox[4][64];
  __shared__ float  sarea[4][64];
  int row0 = rb*64;
  {
    float4 bi0 = boxes[min(row0 + lane, n-1)];
    bi0.x += off; bi0.y += off; bi0.z += off; bi0.w += off;
    sbox[wv][lane] = bi0;
    sarea[wv][lane] = (bi0.z - bi0.x) * (bi0.w - bi0.y);
  }
  bool z0 = (jw0 < rb);                  // word0 entirely below diagonal
  bool d0 = (jw0 == rb), d1 = (jw1 == rb);
  // bracket constants: 0.7f=0x1.666666p-1; c_lo=pred, c_hi=succ^2.
  // inter >= rn(c_hi*u) => inter >= Md*u; inter < rn(c_lo*u) => inter < Md*u.
  const float CHI = 0x1.66666ap-1f;      // 0x3F333335
  const float CLO = 0x1.666664p-1f;      // 0x3F333332
  unsigned long long acc0 = 0ull, acc1 = 0ull, unc = 0ull;
  #pragma unroll 16
  for (int r = 0; r < 64; r++) {
    float4 bi = sbox[wv][r];             // LDS broadcast (uniform address)
    float ai = sarea[wv][r];
    float xx1 = fmaxf(bi.x, b0x), yy1 = fmaxf(bi.y, b0y);
    float xx2 = fminf(bi.z, b0z), yy2 = fminf(bi.w, b0w);
    float iw_ = fmaxf(xx2 - xx1, 0.0f), ih_ = fmaxf(yy2 - yy1, 0.0f);
    float in0 = iw_ * ih_;
    float u0 = fmaxf((ai + a0) - in0, 1e-6f);
    float xc1 = fmaxf(bi.x, b1x), yc1 = fmaxf(bi.y, b1y);
    float xc2 = fminf(bi.z, b1z), yc2 = fminf(bi.w, b1w);
    float jw_ = fmaxf(xc2 - xc1, 0.0f), jh_ = fmaxf(yc2 - yc1, 0.0f);
    float in1 = jw_ * jh_;
    float u1 = fmaxf((ai + a1) - in1, 1e-6f);
    unsigned long long h0 = __ballot(in0 >= CHI * u0);
    unsigned long long l0 = __ballot(in0 >= CLO * u0);
    unsigned long long h1 = __ballot(in1 >= CHI * u1);
    unsigned long long l1 = __ballot(in1 >= CLO * u1);
    unc |= (h0 ^ l0) | (h1 ^ l1);
    unsigned long long dm = ~((2ull << r) - 1ull);   // strictly-upper within word
    unsigned long long m0 = z0 ? 0ull : (d0 ? (h0 & dm) : h0);
    unsigned long long m1 = d1 ? (h1 & dm) : h1;
    if (lane == r) { acc0 = m0; acc1 = m1; }
  }
  if (unc) {                             // rare: exact f64 redo of the whole tile
    const double Md = 0.70000001788139343261718750;  // (0.7f + succ(0.7f))/2 exact
    acc0 = 0ull; acc1 = 0ull;
    #pragma unroll 1
    for (int r = 0; r < 64; r++) {
      float4 bi = sbox[wv][r];
      float ai = sarea[wv][r];
      float xx1 = fmaxf(bi.x, b0x), yy1 = fmaxf(bi.y, b0y);
      float xx2 = fminf(bi.z, b0z), yy2 = fminf(bi.w, b0w);
      float iw_ = fmaxf(xx2 - xx1, 0.0f), ih_ = fmaxf(yy2 - yy1, 0.0f);
      float in0 = iw_ * ih_;
      float u0 = fmaxf((ai + a0) - in0, 1e-6f);
      float xc1 = fmaxf(bi.x, b1x), yc1 = fmaxf(bi.y, b1y);
      float xc2 = fminf(bi.z, b1z), yc2 = fminf(bi.w, b1w);
      float jw_ = fmaxf(xc2 - xc1, 0.0f), jh_ = fmaxf(yc2 - yc1, 0.0f);
      float in1 = jw_ * jh_;
      float u1 = fmaxf((ai + a1) - in1, 1e-6f);
      unsigned long long w0 = __ballot((double)in0 >= Md * (double)u0);
      unsigned long long w1 = __ballot((double)in1 >= Md * (double)u1);
      unsigned long long dm = ~((2ull << r) - 1ull);
      unsigned long long m0 = z0 ? 0ull : (d0 ? (w0 & dm) : w0);
      unsigned long long m1 = d1 ? (w1 & dm) : w1;
      if (lane == r) { acc0 = m0; acc1 = m1; }
    }
  }
  int row = row0 + lane;
  if (row < n) {
    unsigned long long* dst = maskbuf + (size_t)pair*2000*MASK_W + (size_t)row*MASK_W + jw0;
    if (z0) {
      dst[1] = acc1;                     // only the diagonal word exists
    } else {
      ulonglong2 v; v.x = acc0; v.y = acc1;
      *((ulonglong2*)dst) = v;           // 16B-aligned (jw0 even)
    }
  }
}

// ---- K7: EXACT one-pass block-sequential greedy NMS + FUSED prefix counts ----
__global__ void __launch_bounds__(1024) k_nms(const unsigned long long* __restrict__ maskbuf,
                      unsigned long long* __restrict__ keep, int* __restrict__ pkc) {
  int pair = blockIdx.x; int lvl = pair % NLVL;
  int n = KSEL[lvl];
  int nw = (n + 63) >> 6;
  const unsigned long long* mrow = maskbuf + (size_t)pair*2000*MASK_W;
  int tid = threadIdx.x;
  int w  = tid & 31;                 // word owned (0..31)
  int rg = tid >> 5;                 // row group (0..31): rows rg*2, rg*2+1
  __shared__ unsigned long long rem[32];   // suppression from finalized kept boxes
  __shared__ unsigned long long diag[64];  // word k of current block's rows
  __shared__ unsigned long long skw[32];   // kept words (for fused pfx)
  __shared__ unsigned long long sSk;       // final suppressed mask of block k
  __shared__ int lcnt[64];
  if (tid < 32) { rem[tid] = 0ull; skw[tid] = 0ull; }
  __syncthreads();

  unsigned long long A0, A1, B0, B1;
  {
    int r0 = min(rg*2, n-1), r1 = min(rg*2+1, n-1);
    A0 = mrow[(size_t)r0*MASK_W + w];
    A1 = mrow[(size_t)r1*MASK_W + w];
  }
  for (int k = 0; k < nw; k++) {
    if (k + 1 < nw) {                // prefetch block k+1 (consumed next iter)
      int r0 = min(64*(k+1) + rg*2, n-1), r1 = min(64*(k+1) + rg*2 + 1, n-1);
      B0 = mrow[(size_t)r0*MASK_W + w];
      B1 = mrow[(size_t)r1*MASK_W + w];
    }
    if (w == k) { diag[rg*2] = A0; diag[rg*2+1] = A1; }
    __syncthreads();
    if (tid < 64) {                  // wave 0: in-block register Jacobi
      int row = 64*k + tid;
      bool valid = row < n;
      unsigned long long D = valid ? diag[tid] : 0ull;   // already strictly upper
      unsigned long long rk = rem[k];
      unsigned long long S = rk;
      for (int it = 0; it < 64; it++) {
        bool kept = valid && !((S >> tid) & 1ull);
        unsigned long long c = kept ? D : 0ull;
        #pragma unroll
        for (int m = 1; m < 64; m <<= 1) {               // wave-wide OR
          unsigned lo = (unsigned)__shfl_xor((int)(unsigned)(c & 0xffffffffull), m, 64);
          unsigned hi = (unsigned)__shfl_xor((int)(unsigned)(c >> 32), m, 64);
          c |= ((unsigned long long)hi << 32) | (unsigned long long)lo;
        }
        unsigned long long Snew = rk | c;                // uniform across wave
        if (Snew == S) break;                            // fixpoint (<= depth iters)
        S = Snew;
      }
      if (tid == 0) {
        sSk = S;
        int nb = n - 64*k;
        unsigned long long vm = (nb >= 64) ? ~0ull : ((1ull << nb) - 1ull);
        unsigned long long kw = (~S) & vm;
        skw[k] = kw;
        keep[(size_t)pair*MASK_W + k] = kw;
      }
    }
    __syncthreads();
    if (w > k) {                     // accumulate alive rows into later words
      unsigned long long Sk = sSk;
      int r0 = 64*k + rg*2, r1 = r0 + 1;
      unsigned long long m = 0ull;
      if (r0 < n && !((Sk >> (rg*2)) & 1ull))     m |= A0;
      if (r1 < n && !((Sk >> (rg*2+1)) & 1ull))   m |= A1;
      if (m) atomicOr(&rem[w], m);
    }
    __syncthreads();
    A0 = B0; A1 = B1;
  }
  // ---- fused prefix counts; wave 0, skw already masked ----
  if (tid < 64) {
    int lane = tid;
    unsigned long long kw = (lane < nw) ? skw[lane] : 0ull;
    lcnt[lane] = __popcll(kw);       // wave-synchronous LDS (no barrier needed)
    int pre = 0;
    for (int t2 = 0; t2 < lane; t2++) pre += lcnt[t2];
    for (int b = 0; b < 64; b++) {
      int p = lane*64 + b;
      if (p < n) {
        pre += (int)((kw >> b) & 1ull);
        pkc[pair*2048 + p] = pre;
      }
    }
  }
}

// ---- K8: rank kept boxes via per-level prefix counts + 4 binary searches ----
__global__ void __launch_bounds__(256) k_out2(const unsigned long long* __restrict__ sel_key,
                      const float* __restrict__ sel_box,
                      const unsigned long long* __restrict__ keep,
                      const int* __restrict__ pkc,
                      float* __restrict__ out) {
  int img = blockIdx.y;
  int pos = blockIdx.x*256 + threadIdx.x;
  if (pos >= MTOT) return;
  int lvl = pos<2000?0 : pos<4000?1 : pos<6000?2 : pos<8000?3 : 4;
  int local = pos - SOFF[lvl];
  int pair = img*NLVL + lvl;
  unsigned long long kw = keep[(size_t)pair*MASK_W + (local >> 6)];
  if (!((kw >> (local & 63)) & 1ull)) return;
  unsigned long long mykey = sel_key[img*MTOT + pos];
  int rank = pkc[pair*2048 + local] - 1;    // kept before me within my level
  #pragma unroll
  for (int l2 = 0; l2 < NLVL; l2++) {
    if (l2 == lvl) continue;
    const unsigned long long* A = sel_key + img*MTOT + SOFF[l2];
    int lo = 0, hi = KSEL[l2];
    while (lo < hi) {
      int mid = (lo + hi) >> 1;
      if (A[mid] > mykey) lo = mid + 1; else hi = mid;
    }
    if (lo > 0) rank += pkc[(img*NLVL + l2)*2048 + lo - 1];
  }
  if (rank < OUTK) {
    ((float4*)out)[img*OUTK + rank] = ((const float4*)sel_box)[img*MTOT + pos];
    out[NIMG*OUTK*4 + img*OUTK + rank] = __uint_as_float((unsigned)(mykey >> 21));
  }
}

extern "C" void kernel_launch(void* const* d_in, const int* in_sizes, int n_in,
                              void* d_out, int out_size, void* d_ws, size_t ws_size,
                              hipStream_t stream) {
  Ins in;
  // setup_inputs dict order: cls_0, reg_0, cls_1, reg_1, ..., cls_4, reg_4, image_h, image_w
  for (int l = 0; l < 5; l++) {
    in.cls[l] = (const float*)d_in[2*l];
    in.reg[l] = (const float*)d_in[2*l + 1];
  }
  in.ih = (const int*)d_in[10];
  in.iw = (const int*)d_in[11];

  char* ws = (char*)d_ws;
  unsigned* hist              = (unsigned*)(ws + OFF_HIST);
  int* pkc                    = (int*)(ws + OFF_PKC);          // aliases hist (dead after k_compact)
  unsigned* cnt               = (unsigned*)(ws + OFF_CNT);
  unsigned* rnk               = (unsigned*)(ws + OFF_RNK);
  unsigned long long* sel_key = (unsigned long long*)(ws + OFF_SELKEY);
  float* sel_box              = (float*)(ws + OFF_SELBOX);
  unsigned long long* maskbuf = (unsigned long long*)(ws + OFF_MASK);
  unsigned long long* ckey    = (unsigned long long*)(ws + OFF_CKEY);  // aliases maskbuf (dead before k_masks)
  float4* cbox                = (float4*)(ws + OFF_CBOX);              // aliases maskbuf (dead before k_masks)
  unsigned long long* keep    = (unsigned long long*)(ws + OFF_KEEP);
  float* out                  = (float*)d_out;

  // 8 dispatches (was 10): k_scan absorbed into k_compact (redundant per-block
  // recompute across kernel boundary), d_out zeroing absorbed into k_hist.
  hipMemsetAsync(d_ws, 0, ZERO_BYTES, stream);                 // hist + cnt + rnk
  k_hist   <<<NIMG*BLK_PER_IMG, 256, 0, stream>>>(in, hist, (float4*)out);
  k_compact<<<NIMG*BLK_PER_IMG, 256, 0, stream>>>(in, hist, cnt, ckey, cbox);
  k_racc   <<<dim3(CAP/256, CAP/256, NPAIR), 256, 0, stream>>>(cnt, ckey, rnk);
  k_rsel   <<<dim3(CAP/256, NPAIR), 256, 0, stream>>>(cnt, ckey, cbox, rnk, sel_key, sel_box);
  k_masks  <<<dim3(68, NPAIR), 256, 0, stream>>>(sel_box, maskbuf);
  k_nms    <<<NPAIR, 1024, 0, stream>>>(maskbuf, keep, pkc);
  k_out2   <<<dim3((MTOT + 255)/256, NIMG), 256, 0, stream>>>(sel_key, sel_box, keep, pkc, out);
}